// Round 6
// baseline (214.723 us; speedup 1.0000x reference)
//
#include <hip/hip_runtime.h>
#include <math.h>

#define NM 131072
#define PP 256
#define BB 32
#define INF_F 3.0e38f

// Padded LDS slot: stride-16 access patterns become stride-17 (coprime 32).
#define SLOT(x) ((x) + ((x) >> 4))

// Branchless sorted insert into (d0<=d1<=d2) top-3 list.
// Strict < : on ties the incumbent (earlier-scanned = lower index) wins,
// matching lax.top_k. Sub-lists must cover ascending contiguous ranges and
// be merged in range order to preserve this.
__device__ __forceinline__ void ins3(float d, int i,
    float& d0, float& d1, float& d2, int& i0, int& i1, int& i2) {
  bool l0 = d < d0, l1 = d < d1, l2 = d < d2;
  d2 = l1 ? d1 : (l2 ? d : d2);
  i2 = l1 ? i1 : (l2 ? i : i2);
  d1 = l0 ? d0 : (l1 ? d : d1);
  i1 = l0 ? i0 : (l1 ? i : i1);
  d0 = l0 ? d : d0;
  i0 = l0 ? i : i0;
}

// Exact-fp32 distance matching the reference (no fma contraction).
__device__ __forceinline__ float dist2(float ax, float ay, float bx, float by) {
  float dx = ax - bx, dy = ay - by;
  return __fadd_rn(__fmul_rn(dx, dx), __fmul_rn(dy, dy));
}

// ---------- KNN A, fused: block = pivotal point, 1024 threads ----------
// Thread t scans mesh[t*128 .. t*128+128) (ascending); 3-level LDS merge
// 1024 -> 64 -> 8 -> 1 in list order (tie-safe). One dispatch, no global
// intermediates (R5: partial+merge cost 2 dispatches + 12 MB round-trip).
__global__ __launch_bounds__(1024)
void knnA_kernel(const float* __restrict__ mesh, const float* __restrict__ piv,
                 float* __restrict__ wA, int* __restrict__ idxA) {
  const int p = blockIdx.x;
  const int t = threadIdx.x;
  __shared__ float sd0[SLOT(1024)], sd1[SLOT(1024)], sd2[SLOT(1024)];
  __shared__ int   si0[SLOT(1024)], si1[SLOT(1024)], si2[SLOT(1024)];

  const float px = piv[2 * p], py = piv[2 * p + 1];   // block-uniform
  float d0 = INF_F, d1 = INF_F, d2 = INF_F;
  int i0 = 0, i1 = 0, i2 = 0;
  const int base = t * 128;
  const float2* m2 = (const float2*)mesh;
#pragma unroll 4
  for (int i = 0; i < 128; ++i) {
    float2 mv = m2[base + i];                         // per-lane streaming
    ins3(dist2(px, py, mv.x, mv.y), base + i, d0, d1, d2, i0, i1, i2);
  }
  sd0[SLOT(t)] = d0; sd1[SLOT(t)] = d1; sd2[SLOT(t)] = d2;
  si0[SLOT(t)] = i0; si1[SLOT(t)] = i1; si2[SLOT(t)] = i2;
  __syncthreads();

  // Level 1: 64 threads x 16 lists (reads stride 17 -> conflict-free)
  if (t < 64) {
    d0 = d1 = d2 = INF_F; i0 = i1 = i2 = 0;
    for (int j = t * 16; j < t * 16 + 16; ++j) {
      int s = SLOT(j);
      ins3(sd0[s], si0[s], d0, d1, d2, i0, i1, i2);
      ins3(sd1[s], si1[s], d0, d1, d2, i0, i1, i2);
      ins3(sd2[s], si2[s], d0, d1, d2, i0, i1, i2);
    }
  }
  __syncthreads();
  if (t < 64) {
    sd0[SLOT(t)] = d0; sd1[SLOT(t)] = d1; sd2[SLOT(t)] = d2;
    si0[SLOT(t)] = i0; si1[SLOT(t)] = i1; si2[SLOT(t)] = i2;
  }
  __syncthreads();

  // Level 2: 8 threads x 8 lists
  if (t < 8) {
    d0 = d1 = d2 = INF_F; i0 = i1 = i2 = 0;
    for (int j = t * 8; j < t * 8 + 8; ++j) {
      int s = SLOT(j);
      ins3(sd0[s], si0[s], d0, d1, d2, i0, i1, i2);
      ins3(sd1[s], si1[s], d0, d1, d2, i0, i1, i2);
      ins3(sd2[s], si2[s], d0, d1, d2, i0, i1, i2);
    }
  }
  __syncthreads();
  if (t < 8) {
    sd0[SLOT(t)] = d0; sd1[SLOT(t)] = d1; sd2[SLOT(t)] = d2;
    si0[SLOT(t)] = i0; si1[SLOT(t)] = i1; si2[SLOT(t)] = i2;
  }
  __syncthreads();

  // Level 3: thread 0 merges 8 -> final top-3, writes weights
  if (t == 0) {
    d0 = d1 = d2 = INF_F; i0 = i1 = i2 = 0;
    for (int j = 0; j < 8; ++j) {
      int s = SLOT(j);
      ins3(sd0[s], si0[s], d0, d1, d2, i0, i1, i2);
      ins3(sd1[s], si1[s], d0, d1, d2, i0, i1, i2);
      ins3(sd2[s], si2[s], d0, d1, d2, i0, i1, i2);
    }
    wA[p * 3 + 0] = 1.0f / fmaxf(d0, 1e-16f); idxA[p * 3 + 0] = i0;
    wA[p * 3 + 1] = 1.0f / fmaxf(d1, 1e-16f); idxA[p * 3 + 1] = i1;
    wA[p * 3 + 2] = 1.0f / fmaxf(d2, 1e-16f); idxA[p * 3 + 2] = i2;
  }
}

// ---------- fused: gather+LN+interp -> y ; q = y@Wf^T+...; Q/K proj ----------
// Also zeroes this block's y2 slice (replaces the memset dispatch; attn's
// atomics need zeros and launches after us in stream order).
// __launch_bounds__(128, 2): VGPR budget 256/wave so wreg[64] stays in
// registers (R3 post-mortem: default 64-VGPR cap spilled it -> 115 MB of
// scratch traffic).
__global__ __launch_bounds__(128, 2)
void qqk_kernel(const float* __restrict__ node, const float* __restrict__ piv,
                const float* __restrict__ wA, const int* __restrict__ idxA,
                const float* __restrict__ gamma, const float* __restrict__ beta,
                const float* __restrict__ Wf, const float* __restrict__ bf,
                const float* __restrict__ Wp, const float* __restrict__ bp,
                const float* __restrict__ ipw, const float* __restrict__ ipb,
                float* __restrict__ y, float* __restrict__ Qh,
                float* __restrict__ Kh, float* __restrict__ y2) {
  const int b = blockIdx.x >> 5;
  const int ptile = (blockIdx.x & 31) * 8;
  const int t = threadIdx.x;
  __shared__ float pnum[8][3][3];
  __shared__ float pden[8][3];
  __shared__ float ysm[8][3];
  __shared__ float qs[8][64];

  if (t < 24) {
    // zero y2 slice for attn's atomics (disjoint across blocks)
    y2[(b * PP + ptile) * 3 + t] = 0.f;
    // gather + LayerNorm partial: t -> (row r, neighbor k)
    int r = t / 3, k = t % 3;
    int p = ptile + r;
    int idx = idxA[p * 3 + k];
    float w = wA[p * 3 + k];
    const float* rw = node + ((size_t)b * NM + idx) * 3;
    float a0 = rw[0], a1 = rw[1], a2 = rw[2];
    float mu = (a0 + a1 + a2) * (1.0f / 3.0f);
    float e0 = a0 - mu, e1 = a1 - mu, e2 = a2 - mu;
    float var = (e0 * e0 + e1 * e1 + e2 * e2) * (1.0f / 3.0f);
    float sc = 1.0f / sqrtf(var + 1e-5f);
    pnum[r][k][0] = (e0 * sc * gamma[0] + beta[0]) * w;
    pnum[r][k][1] = (e1 * sc * gamma[1] + beta[1]) * w;
    pnum[r][k][2] = (e2 * sc * gamma[2] + beta[2]) * w;
    pden[r][k] = w;
  }
  __syncthreads();
  if (t < 8) {
    // k-order sums match the previous sequential k-loop exactly
    float n0 = (pnum[t][0][0] + pnum[t][1][0]) + pnum[t][2][0];
    float n1 = (pnum[t][0][1] + pnum[t][1][1]) + pnum[t][2][1];
    float n2 = (pnum[t][0][2] + pnum[t][1][2]) + pnum[t][2][2];
    float den = (pden[t][0] + pden[t][1]) + pden[t][2];
    float y0 = n0 / den, y1 = n1 / den, yv2 = n2 / den;
    ysm[t][0] = y0; ysm[t][1] = y1; ysm[t][2] = yv2;
    float* yg = y + (b * PP + ptile + t) * 3;
    yg[0] = y0; yg[1] = y1; yg[2] = yv2;
  }
  __syncthreads();

  const int e = t & 63;
  const int half = t >> 6;  // 0 -> Q, 1 -> K
  {
    float wf0 = Wf[e * 3], wf1 = Wf[e * 3 + 1], wf2 = Wf[e * 3 + 2];
    float wp0 = Wp[e * 2], wp1 = Wp[e * 2 + 1];
    float cst = bf[e] + bp[e];
    for (int r = half; r < 8; r += 2) {
      int p = ptile + r;
      float pe = piv[2 * p] * wp0 + piv[2 * p + 1] * wp1;
      qs[r][e] = ysm[r][0] * wf0 + ysm[r][1] * wf1 + ysm[r][2] * wf2 + cst + pe;
    }
  }
  __syncthreads();

  const int row = half * 64 + e;
  float wreg[64];
  const float4* W4 = (const float4*)(ipw + row * 64);
#pragma unroll
  for (int j = 0; j < 16; ++j) {
    float4 v = W4[j];
    wreg[4 * j] = v.x; wreg[4 * j + 1] = v.y; wreg[4 * j + 2] = v.z; wreg[4 * j + 3] = v.w;
  }
  float bias = ipb[row];
  float* dst = half ? Kh : Qh;
  const int h = e >> 4, d = e & 15;
  for (int r = 0; r < 8; ++r) {
    float acc = bias;
#pragma unroll
    for (int j = 0; j < 64; ++j) acc += qs[r][j] * wreg[j];
    int p = ptile + r;
    dst[(((b * 4 + h) * PP) + p) * 16 + d] = acc;
  }
}

// ---------- attention: block = (b, h, q-half); thread = q-row; online softmax ----------
__global__ void attn_kernel(const float* __restrict__ Qh, const float* __restrict__ Kh,
                            const float* __restrict__ y, float* __restrict__ y2) {
  const int b = blockIdx.x >> 3;
  const int h = (blockIdx.x >> 1) & 3;
  const int qh = blockIdx.x & 1;
  const int t = threadIdx.x;          // 128 threads
  const int q = qh * 128 + t;

  __shared__ float Ks[PP * 16];       // 16 KB, head h's K
  __shared__ float ys[PP * 3];        // 3 KB

  {
    const float4* src = (const float4*)(Kh + (size_t)(b * 4 + h) * PP * 16);
    float4* dst = (float4*)Ks;
#pragma unroll
    for (int j = 0; j < 8; ++j) dst[j * 128 + t] = src[j * 128 + t];
    const float* ysrc = y + b * PP * 3;
#pragma unroll
    for (int j = 0; j < 6; ++j) ys[j * 128 + t] = ysrc[j * 128 + t];
  }
  __syncthreads();

  const float4* q4 = (const float4*)(Qh + ((size_t)((b * 4 + h) * PP) + q) * 16);
  float4 qa = q4[0], qb = q4[1], qc = q4[2], qd = q4[3];

  float m = -INF_F, l = 0.f, a0 = 0.f, a1 = 0.f, a2 = 0.f;
#pragma unroll 4
  for (int k = 0; k < PP; ++k) {
    const float4* kr = (const float4*)(Ks + k * 16);   // broadcast read
    float4 k0 = kr[0], k1 = kr[1], k2 = kr[2], k3 = kr[3];
    float dot = qa.x * k0.x + qa.y * k0.y + qa.z * k0.z + qa.w * k0.w
              + qb.x * k1.x + qb.y * k1.y + qb.z * k1.z + qb.w * k1.w
              + qc.x * k2.x + qc.y * k2.y + qc.z * k2.z + qc.w * k2.w
              + qd.x * k3.x + qd.y * k3.y + qd.z * k3.z + qd.w * k3.w;
    float s = dot * 0.25f;            // 1/sqrt(DH=16)
    float mn = fmaxf(m, s);
    float p = __expf(s - mn);
    float sc = __expf(m - mn);
    float y0 = ys[k * 3], y1 = ys[k * 3 + 1], yy2 = ys[k * 3 + 2];
    l = l * sc + p;
    a0 = a0 * sc + p * y0;
    a1 = a1 * sc + p * y1;
    a2 = a2 * sc + p * yy2;
    m = mn;
  }
  float inv = 0.25f / l;              // mean over 4 heads
  float* o = y2 + (b * PP + q) * 3;
  atomicAdd(o + 0, a0 * inv);
  atomicAdd(o + 1, a1 * inv);
  atomicAdd(o + 2, a2 * inv);
}

// ---------- KNN B + output: block = 64 mesh pts x 4 subs; 8192 waves ----------
#define LDW 13
__global__ __launch_bounds__(256)
void knnB_out(const float* __restrict__ mesh, const float* __restrict__ piv,
              const float* __restrict__ y2, float* __restrict__ out) {
  const int tid = threadIdx.x;
  const int ml = tid & 63;
  const int sub = tid >> 6;          // wave-uniform
  const int m = blockIdx.x * 64 + ml;
  __shared__ float sdf[64 * LDW];
  __shared__ int   sif[64 * LDW];

  const float2 mv = ((const float2*)mesh)[m];  // per-lane, coalesced
  float d0 = INF_F, d1 = INF_F, d2 = INF_F;
  int i0 = 0, i1 = 0, i2 = 0;
  const int base = sub * 64;
  const float2* p2 = (const float2*)piv;
#pragma unroll 4
  for (int i = 0; i < 64; ++i) {
    int idx = base + i;
    float2 pv = p2[idx];             // wave-broadcast line
    ins3(dist2(mv.x, mv.y, pv.x, pv.y), idx, d0, d1, d2, i0, i1, i2);
  }
  sdf[ml * LDW + sub * 3 + 0] = d0; sif[ml * LDW + sub * 3 + 0] = i0;
  sdf[ml * LDW + sub * 3 + 1] = d1; sif[ml * LDW + sub * 3 + 1] = i1;
  sdf[ml * LDW + sub * 3 + 2] = d2; sif[ml * LDW + sub * 3 + 2] = i2;
  __syncthreads();

  // all 4 sub-threads duplicate the merge for their ml (cheap, conflict-free)
  float e0 = sdf[ml * LDW + 0], e1 = sdf[ml * LDW + 1], e2 = sdf[ml * LDW + 2];
  int j0 = sif[ml * LDW + 0], j1 = sif[ml * LDW + 1], j2 = sif[ml * LDW + 2];
#pragma unroll
  for (int s = 1; s < 4; ++s)
#pragma unroll
    for (int k = 0; k < 3; ++k)
      ins3(sdf[ml * LDW + s * 3 + k], sif[ml * LDW + s * 3 + k], e0, e1, e2, j0, j1, j2);

  float w0 = 1.0f / fmaxf(e0, 1e-16f);
  float w1 = 1.0f / fmaxf(e1, 1e-16f);
  float w2 = 1.0f / fmaxf(e2, 1e-16f);
  float inv = 1.0f / (w0 + w1 + w2);
  const int o0 = j0 * 3, o1 = j1 * 3, o2 = j2 * 3;

#pragma unroll 2
  for (int bi = 0; bi < 8; ++bi) {
    const int b = sub * 8 + bi;                       // wave-uniform
    const float* yb = y2 + b * PP * 3;
    float3 r0 = *(const float3*)(yb + o0);
    float3 r1 = *(const float3*)(yb + o1);
    float3 r2 = *(const float3*)(yb + o2);
    float3 res;
    res.x = (w0 * r0.x + w1 * r1.x + w2 * r2.x) * inv;
    res.y = (w0 * r0.y + w1 * r1.y + w2 * r2.y) * inv;
    res.z = (w0 * r0.z + w1 * r1.z + w2 * r2.z) * inv;
    *(float3*)(out + ((size_t)b * NM + m) * 3) = res; // lane-contiguous 12 B
  }
}

extern "C" void kernel_launch(void* const* d_in, const int* in_sizes, int n_in,
                              void* d_out, int out_size, void* d_ws, size_t ws_size,
                              hipStream_t stream) {
  const float* node  = (const float*)d_in[0];
  const float* mesh  = (const float*)d_in[1];
  const float* piv   = (const float*)d_in[2];
  const float* gamma = (const float*)d_in[3];
  const float* beta  = (const float*)d_in[4];
  const float* Wf    = (const float*)d_in[5];
  const float* bf    = (const float*)d_in[6];
  const float* Wp    = (const float*)d_in[7];
  const float* bp    = (const float*)d_in[8];
  const float* ipw   = (const float*)d_in[9];
  const float* ipb   = (const float*)d_in[10];
  float* out = (float*)d_out;

  // workspace layout (floats)
  float* wA   = (float*)d_ws;            // PP*3
  int*   idxA = (int*)(wA + PP * 3);     // PP*3
  float* y    = (float*)(idxA + PP * 3); // BB*PP*3
  float* Qh   = y + BB * PP * 3;         // BB*4*PP*16
  float* Kh   = Qh + BB * PP * 64;       // BB*4*PP*16
  float* y2   = Kh + BB * PP * 64;       // BB*PP*3

  knnA_kernel<<<PP, 1024, 0, stream>>>(mesh, piv, wA, idxA);
  qqk_kernel<<<BB * 32, 128, 0, stream>>>(node, piv, wA, idxA, gamma, beta,
                                          Wf, bf, Wp, bp, ipw, ipb, y, Qh, Kh, y2);
  attn_kernel<<<BB * 4 * 2, 128, 0, stream>>>(Qh, Kh, y, y2);
  knnB_out<<<NM / 64, 256, 0, stream>>>(mesh, piv, y2, out);
}

// Round 7
// 212.571 us; speedup vs baseline: 1.0101x; 1.0101x over previous
//
#include <hip/hip_runtime.h>
#include <math.h>

#define NM 131072
#define PP 256
#define BB 32
#define INF_F 3.0e38f
#define KMAX 0xFFFFFFFFFFFFFFFFull

// ---- u64 sort key: (fp32 bits of d^2) << 32 | index ----
// d^2 >= 0 so fp32 bits are monotone in value; unsigned compare reproduces
// lax.top_k's (distance, then smallest-index) order EXACTLY, making every
// scan/merge order tie-safe. Index rides along for free.
__device__ __forceinline__ unsigned long long mkkey(float d, int i) {
  return ((unsigned long long)__float_as_uint(d) << 32) | (unsigned int)i;
}

// Branchless sorted insert of key into (k0<=k1<=k2).
__device__ __forceinline__ void insK(unsigned long long k,
    unsigned long long& k0, unsigned long long& k1, unsigned long long& k2) {
  bool l0 = k < k0, l1 = k < k1, l2 = k < k2;
  k2 = l1 ? k1 : (l2 ? k : k2);
  k1 = l0 ? k0 : (l1 ? k : k1);
  k0 = l0 ? k : k0;
}

// Exact-fp32 distance matching the reference (no fma contraction).
__device__ __forceinline__ float dist2(float ax, float ay, float bx, float by) {
  float dx = ax - bx, dy = ay - by;
  return __fadd_rn(__fmul_rn(dx, dx), __fmul_rn(dy, dy));
}

// ---------- KNN A: block = pivotal point, 1024 threads, COALESCED scan ----------
// R6 post-mortem: per-lane 1KB-stride loads = 64 cache lines per wave instr
// -> TA-serialized, 43 us. Now lane-interleaved (idx = it*1024 + t): 512 B
// contiguous per wave load. u64 keys make the merge order irrelevant.
__global__ __launch_bounds__(1024)
void knnA_kernel(const float* __restrict__ mesh, const float* __restrict__ piv,
                 float* __restrict__ wA, int* __restrict__ idxA) {
  const int p = blockIdx.x;
  const int t = threadIdx.x;
  __shared__ unsigned long long ws[48];   // 16 waves x 3 keys

  const float px = piv[2 * p], py = piv[2 * p + 1];   // block-uniform
  unsigned long long k0 = KMAX, k1 = KMAX, k2 = KMAX;
  const float2* m2 = (const float2*)mesh;
#pragma unroll 4
  for (int it = 0; it < 128; ++it) {
    int idx = it * 1024 + t;                          // lanes consecutive
    float2 mv = m2[idx];                              // 512 B/wave, coalesced
    insK(mkkey(dist2(px, py, mv.x, mv.y), idx), k0, k1, k2);
  }

  // wave butterfly: all lanes converge to wave top-3
#pragma unroll
  for (int off = 32; off >= 1; off >>= 1) {
    unsigned long long a0 = __shfl_xor(k0, off, 64);
    unsigned long long a1 = __shfl_xor(k1, off, 64);
    unsigned long long a2 = __shfl_xor(k2, off, 64);
    insK(a0, k0, k1, k2); insK(a1, k0, k1, k2); insK(a2, k0, k1, k2);
  }
  if ((t & 63) == 0) {
    int w = t >> 6;
    ws[w * 3 + 0] = k0; ws[w * 3 + 1] = k1; ws[w * 3 + 2] = k2;
  }
  __syncthreads();

  // wave 0: lane-parallel top-3 of the 48 wave-results via butterfly
  if (t < 64) {
    unsigned long long f0 = (t < 48) ? ws[t] : KMAX;
    unsigned long long f1 = KMAX, f2 = KMAX;
#pragma unroll
    for (int off = 32; off >= 1; off >>= 1) {
      unsigned long long a0 = __shfl_xor(f0, off, 64);
      unsigned long long a1 = __shfl_xor(f1, off, 64);
      unsigned long long a2 = __shfl_xor(f2, off, 64);
      insK(a0, f0, f1, f2); insK(a1, f0, f1, f2); insK(a2, f0, f1, f2);
    }
    if (t == 0) {
      float d0 = __uint_as_float((unsigned)(f0 >> 32));
      float d1 = __uint_as_float((unsigned)(f1 >> 32));
      float d2 = __uint_as_float((unsigned)(f2 >> 32));
      wA[p * 3 + 0] = 1.0f / fmaxf(d0, 1e-16f); idxA[p * 3 + 0] = (int)(unsigned)f0;
      wA[p * 3 + 1] = 1.0f / fmaxf(d1, 1e-16f); idxA[p * 3 + 1] = (int)(unsigned)f1;
      wA[p * 3 + 2] = 1.0f / fmaxf(d2, 1e-16f); idxA[p * 3 + 2] = (int)(unsigned)f2;
    }
  }
}

// ---------- fused: gather+LN+interp -> y ; q proj ; Q/K proj ----------
// Zeroes this block's y2 slice (stride-4 rows). __launch_bounds__(128,2):
// VGPR budget 256/wave so wreg[64] stays in registers (R3 post-mortem).
__global__ __launch_bounds__(128, 2)
void qqk_kernel(const float* __restrict__ node, const float* __restrict__ piv,
                const float* __restrict__ wA, const int* __restrict__ idxA,
                const float* __restrict__ gamma, const float* __restrict__ beta,
                const float* __restrict__ Wf, const float* __restrict__ bf,
                const float* __restrict__ Wp, const float* __restrict__ bp,
                const float* __restrict__ ipw, const float* __restrict__ ipb,
                float* __restrict__ y, float* __restrict__ Qh,
                float* __restrict__ Kh, float* __restrict__ y2) {
  const int b = blockIdx.x >> 5;
  const int ptile = (blockIdx.x & 31) * 8;
  const int t = threadIdx.x;
  __shared__ float pnum[8][3][3];
  __shared__ float pden[8][3];
  __shared__ float ysm[8][3];
  __shared__ float qs[8][64];

  if (t < 32) y2[(b * PP + ptile) * 4 + t] = 0.f;   // 8 rows x 4 (padded)
  if (t < 24) {
    int r = t / 3, k = t % 3;
    int p = ptile + r;
    int idx = idxA[p * 3 + k];
    float w = wA[p * 3 + k];
    const float* rw = node + ((size_t)b * NM + idx) * 3;
    float a0 = rw[0], a1 = rw[1], a2 = rw[2];
    float mu = (a0 + a1 + a2) * (1.0f / 3.0f);
    float e0 = a0 - mu, e1 = a1 - mu, e2 = a2 - mu;
    float var = (e0 * e0 + e1 * e1 + e2 * e2) * (1.0f / 3.0f);
    float sc = 1.0f / sqrtf(var + 1e-5f);
    pnum[r][k][0] = (e0 * sc * gamma[0] + beta[0]) * w;
    pnum[r][k][1] = (e1 * sc * gamma[1] + beta[1]) * w;
    pnum[r][k][2] = (e2 * sc * gamma[2] + beta[2]) * w;
    pden[r][k] = w;
  }
  __syncthreads();
  if (t < 8) {
    float n0 = (pnum[t][0][0] + pnum[t][1][0]) + pnum[t][2][0];
    float n1 = (pnum[t][0][1] + pnum[t][1][1]) + pnum[t][2][1];
    float n2 = (pnum[t][0][2] + pnum[t][1][2]) + pnum[t][2][2];
    float den = (pden[t][0] + pden[t][1]) + pden[t][2];
    float y0 = n0 / den, y1 = n1 / den, yv2 = n2 / den;
    ysm[t][0] = y0; ysm[t][1] = y1; ysm[t][2] = yv2;
    float* yg = y + (b * PP + ptile + t) * 3;
    yg[0] = y0; yg[1] = y1; yg[2] = yv2;
  }
  __syncthreads();

  const int e = t & 63;
  const int half = t >> 6;  // 0 -> Q, 1 -> K
  {
    float wf0 = Wf[e * 3], wf1 = Wf[e * 3 + 1], wf2 = Wf[e * 3 + 2];
    float wp0 = Wp[e * 2], wp1 = Wp[e * 2 + 1];
    float cst = bf[e] + bp[e];
    for (int r = half; r < 8; r += 2) {
      int p = ptile + r;
      float pe = piv[2 * p] * wp0 + piv[2 * p + 1] * wp1;
      qs[r][e] = ysm[r][0] * wf0 + ysm[r][1] * wf1 + ysm[r][2] * wf2 + cst + pe;
    }
  }
  __syncthreads();

  const int row = half * 64 + e;
  float wreg[64];
  const float4* W4 = (const float4*)(ipw + row * 64);
#pragma unroll
  for (int j = 0; j < 16; ++j) {
    float4 v = W4[j];
    wreg[4 * j] = v.x; wreg[4 * j + 1] = v.y; wreg[4 * j + 2] = v.z; wreg[4 * j + 3] = v.w;
  }
  float bias = ipb[row];
  float* dst = half ? Kh : Qh;
  const int h = e >> 4, d = e & 15;
  for (int r = 0; r < 8; ++r) {
    float acc = bias;
#pragma unroll
    for (int j = 0; j < 64; ++j) acc += qs[r][j] * wreg[j];
    int p = ptile + r;
    dst[(((b * 4 + h) * PP) + p) * 16 + d] = acc;
  }
}

// ---------- attention: block = (b, h, q-half); thread = q-row; online softmax ----------
__global__ void attn_kernel(const float* __restrict__ Qh, const float* __restrict__ Kh,
                            const float* __restrict__ y, float* __restrict__ y2) {
  const int b = blockIdx.x >> 3;
  const int h = (blockIdx.x >> 1) & 3;
  const int qh = blockIdx.x & 1;
  const int t = threadIdx.x;          // 128 threads
  const int q = qh * 128 + t;

  __shared__ float Ks[PP * 16];       // 16 KB, head h's K
  __shared__ float ys[PP * 3];        // 3 KB

  {
    const float4* src = (const float4*)(Kh + (size_t)(b * 4 + h) * PP * 16);
    float4* dst = (float4*)Ks;
#pragma unroll
    for (int j = 0; j < 8; ++j) dst[j * 128 + t] = src[j * 128 + t];
    const float* ysrc = y + b * PP * 3;
#pragma unroll
    for (int j = 0; j < 6; ++j) ys[j * 128 + t] = ysrc[j * 128 + t];
  }
  __syncthreads();

  const float4* q4 = (const float4*)(Qh + ((size_t)((b * 4 + h) * PP) + q) * 16);
  float4 qa = q4[0], qb = q4[1], qc = q4[2], qd = q4[3];

  float m = -INF_F, l = 0.f, a0 = 0.f, a1 = 0.f, a2 = 0.f;
#pragma unroll 4
  for (int k = 0; k < PP; ++k) {
    const float4* kr = (const float4*)(Ks + k * 16);   // broadcast read
    float4 k0 = kr[0], k1 = kr[1], k2 = kr[2], k3 = kr[3];
    float dot = qa.x * k0.x + qa.y * k0.y + qa.z * k0.z + qa.w * k0.w
              + qb.x * k1.x + qb.y * k1.y + qb.z * k1.z + qb.w * k1.w
              + qc.x * k2.x + qc.y * k2.y + qc.z * k2.z + qc.w * k2.w
              + qd.x * k3.x + qd.y * k3.y + qd.z * k3.z + qd.w * k3.w;
    float s = dot * 0.25f;            // 1/sqrt(DH=16)
    float mn = fmaxf(m, s);
    float p = __expf(s - mn);
    float sc = __expf(m - mn);
    float y0 = ys[k * 3], y1 = ys[k * 3 + 1], yy2 = ys[k * 3 + 2];
    l = l * sc + p;
    a0 = a0 * sc + p * y0;
    a1 = a1 * sc + p * y1;
    a2 = a2 * sc + p * yy2;
    m = mn;
  }
  float inv = 0.25f / l;              // mean over 4 heads
  float* o = y2 + (b * PP + q) * 4;   // stride-4 (padded) rows
  atomicAdd(o + 0, a0 * inv);
  atomicAdd(o + 1, a1 * inv);
  atomicAdd(o + 2, a2 * inv);
}

// ---------- KNN B + output: block = 64 mesh pts x 4 subs; u64 keys ----------
#define LDWB 13   // u64 stride; 26 words, gcd(26,32)=2 -> ~conflict-free
__global__ __launch_bounds__(256)
void knnB_out(const float* __restrict__ mesh, const float* __restrict__ piv,
              const float* __restrict__ y2, float* __restrict__ out) {
  const int tid = threadIdx.x;
  const int ml = tid & 63;
  const int sub = tid >> 6;          // wave-uniform
  const int m = blockIdx.x * 64 + ml;
  __shared__ unsigned long long sk[64 * LDWB];

  const float2 mv = ((const float2*)mesh)[m];  // per-lane, coalesced
  unsigned long long k0 = KMAX, k1 = KMAX, k2 = KMAX;
  const int base = sub * 64;
  const float2* p2 = (const float2*)piv;
#pragma unroll 4
  for (int i = 0; i < 64; ++i) {
    int idx = base + i;
    float2 pv = p2[idx];             // wave-uniform -> scalar load
    insK(mkkey(dist2(mv.x, mv.y, pv.x, pv.y), idx), k0, k1, k2);
  }
  sk[ml * LDWB + sub * 3 + 0] = k0;
  sk[ml * LDWB + sub * 3 + 1] = k1;
  sk[ml * LDWB + sub * 3 + 2] = k2;
  __syncthreads();

  // all 4 sub-threads duplicate the merge for their ml (order-free with keys)
  unsigned long long e0 = KMAX, e1 = KMAX, e2 = KMAX;
#pragma unroll
  for (int j = 0; j < 12; ++j) insK(sk[ml * LDWB + j], e0, e1, e2);

  float d0 = __uint_as_float((unsigned)(e0 >> 32));
  float d1 = __uint_as_float((unsigned)(e1 >> 32));
  float d2 = __uint_as_float((unsigned)(e2 >> 32));
  int j0 = (int)(unsigned)e0, j1 = (int)(unsigned)e1, j2 = (int)(unsigned)e2;
  float w0 = 1.0f / fmaxf(d0, 1e-16f);
  float w1 = 1.0f / fmaxf(d1, 1e-16f);
  float w2 = 1.0f / fmaxf(d2, 1e-16f);
  float inv = 1.0f / (w0 + w1 + w2);

#pragma unroll 2
  for (int bi = 0; bi < 8; ++bi) {
    const int b = sub * 8 + bi;                       // wave-uniform
    const float4* yb = (const float4*)(y2 + b * PP * 4);
    float4 r0 = yb[j0];                               // 16B-aligned gathers
    float4 r1 = yb[j1];
    float4 r2 = yb[j2];
    float3 res;
    res.x = (w0 * r0.x + w1 * r1.x + w2 * r2.x) * inv;
    res.y = (w0 * r0.y + w1 * r1.y + w2 * r2.y) * inv;
    res.z = (w0 * r0.z + w1 * r1.z + w2 * r2.z) * inv;
    *(float3*)(out + ((size_t)b * NM + m) * 3) = res; // lane-contiguous 12 B
  }
}

extern "C" void kernel_launch(void* const* d_in, const int* in_sizes, int n_in,
                              void* d_out, int out_size, void* d_ws, size_t ws_size,
                              hipStream_t stream) {
  const float* node  = (const float*)d_in[0];
  const float* mesh  = (const float*)d_in[1];
  const float* piv   = (const float*)d_in[2];
  const float* gamma = (const float*)d_in[3];
  const float* beta  = (const float*)d_in[4];
  const float* Wf    = (const float*)d_in[5];
  const float* bf    = (const float*)d_in[6];
  const float* Wp    = (const float*)d_in[7];
  const float* bp    = (const float*)d_in[8];
  const float* ipw   = (const float*)d_in[9];
  const float* ipb   = (const float*)d_in[10];
  float* out = (float*)d_out;

  // workspace layout (floats)
  float* wA   = (float*)d_ws;            // PP*3
  int*   idxA = (int*)(wA + PP * 3);     // PP*3
  float* y    = (float*)(idxA + PP * 3); // BB*PP*3
  float* Qh   = y + BB * PP * 3;         // BB*4*PP*16
  float* Kh   = Qh + BB * PP * 64;       // BB*4*PP*16
  float* y2   = Kh + BB * PP * 64;       // BB*PP*4 (padded rows)

  knnA_kernel<<<PP, 1024, 0, stream>>>(mesh, piv, wA, idxA);
  qqk_kernel<<<BB * 32, 128, 0, stream>>>(node, piv, wA, idxA, gamma, beta,
                                          Wf, bf, Wp, bp, ipw, ipb, y, Qh, Kh, y2);
  attn_kernel<<<BB * 4 * 2, 128, 0, stream>>>(Qh, Kh, y, y2);
  knnB_out<<<NM / 64, 256, 0, stream>>>(mesh, piv, y2, out);
}